// Round 5
// baseline (332.425 us; speedup 1.0000x reference)
//
#include <hip/hip_runtime.h>
#include <hip/hip_bf16.h>

// Problem: B=4, S=4096, H=16, D=64. Per (b,s): 16x16 attention over HEADS.
//   scores = (Q @ K^T)/8 ; attn = softmax(scores, g) ; out = (attn @ V) * mask
// Inputs: qkv fp32 [npos][3][16][64]; mask (auto-detected bool/int32/int64).
// Output: fp32 [npos][16][64].
// Block = 256 threads = 4 waves = 4 positions. 48 KB LDS staging:
//   - global->LDS fully coalesced float4 streams (12 loads/thread)
//   - V transposed into LDS so PV fragments are contiguous b128 reads
//   - XOR bank swizzle on Q/K and VT layouts (<=2-way conflicts)
//   - output staged through LDS -> 4 coalesced dwordx4 stores/wave
// Math: bf16 hi/lo split MFMA (fp32-accurate), unchanged from passing round.

typedef __attribute__((ext_vector_type(8))) short short8;
typedef __attribute__((ext_vector_type(4))) float floatx4;

static __device__ __forceinline__ short f2bf(float x) {
    union { __hip_bfloat16 b; short s; } u; u.b = __float2bfloat16(x);  // RNE
    return u.s;
}
static __device__ __forceinline__ float bf2f(short s) {
    union { float f; unsigned int u; } u;
    u.u = ((unsigned int)(unsigned short)s) << 16;
    return u.f;
}
static __device__ __forceinline__ void split8(floatx4 a, floatx4 b,
                                              short8& hi, short8& lo) {
    float v[8] = {a[0], a[1], a[2], a[3], b[0], b[1], b[2], b[3]};
    #pragma unroll
    for (int j = 0; j < 8; ++j) {
        short h = f2bf(v[j]);
        hi[j] = h;
        lo[j] = f2bf(v[j] - bf2f(h));
    }
}

// ---- mask storage-format detector: 0 = 1-byte bool, 1 = int32, 2 = int64 ---
__global__ void detect_mask_fmt(const unsigned char* __restrict__ mb, int npos,
                                int* __restrict__ flag)
{
    __shared__ int found1, found2;
    if (threadIdx.x == 0) { found1 = 0; found2 = 0; }
    __syncthreads();
    int l1 = 0;
    for (int i = threadIdx.x; i < npos; i += blockDim.x)
        if ((i & 3) != 0 && mb[i] != 0) l1 = 1;
    if (l1) atomicOr(&found1, 1);
    __syncthreads();
    if (found1 == 0) {
        int l2 = 0;
        for (int i = threadIdx.x; i < npos / 2; i += blockDim.x)
            if (mb[8 * i + 4] != 0) l2 = 1;
        if (l2) atomicOr(&found2, 1);
        __syncthreads();
    } else {
        __syncthreads();
    }
    if (threadIdx.x == 0) *flag = found1 ? 0 : (found2 ? 1 : 2);
}

// LDS layout per position (3072 floats = 12 KB):
//   words [0,2048): Q rows 0..15, K rows 16..31; row pitch 64, column words
//                   stored at (col ^ ((row&3)<<3))  [XOR swizzle, bits 3..4]
//   words [2048,3072): V^T, VT[d][g] at 2048 + d*16 + (g ^ ((d&1)<<3))
__global__ __launch_bounds__(256) void fa_heads_kernel(
    const float* __restrict__ qkv,              // [npos][3][16][64] fp32
    const unsigned char* __restrict__ maskraw,  // [npos] bool/int32/int64
    const int* __restrict__ fmt,                // from detector
    float* __restrict__ out,                    // [npos][16][64] fp32
    int npos)
{
    __shared__ float lds[4 * 3072];             // 48 KB

    const int tid  = threadIdx.x;
    const int w    = tid >> 6;                  // wave id = position in block
    const int lane = tid & 63;
    const int posBase = blockIdx.x << 2;

    // ================= stage 4 positions, fully coalesced ===================
    {
        const int r     = tid >> 4;             // 0..15
        const int cbase = (tid & 15) << 2;      // 0,4,...,60
        #pragma unroll
        for (int p = 0; p < 4; ++p) {
            const int pos = posBase + p;
            if (pos >= npos) break;
            const float* src = qkv + (size_t)pos * 3072 + tid * 4;
            const int po = p * 3072;
            // it=0: Q rows, it=1: K rows (swizzled row-major)
            #pragma unroll
            for (int it = 0; it < 2; ++it) {
                floatx4 v = *(const floatx4*)(src + it * 1024);
                const int row = it * 16 + r;
                const int sw  = (row & 3) << 3;
                *(floatx4*)&lds[po + row * 64 + (cbase ^ sw)] = v;
            }
            // it=2: V, transposed into VT[d][g]
            {
                floatx4 v = *(const floatx4*)(src + 2048);
                #pragma unroll
                for (int i = 0; i < 4; ++i) {
                    const int d = cbase + i;    // 0..63
                    lds[po + 2048 + d * 16 + (r ^ ((d & 1) << 3))] = v[i];
                }
            }
        }
    }
    __syncthreads();

    // ================= per-wave attention on its position ===================
    const int wid = posBase + w;
    if (wid >= npos) return;
    const int t  = lane & 15;
    const int qa = lane >> 4;
    const int po = w * 3072;

    // ---- Q/K fragments from swizzled LDS -----------------------------------
    // row t (Q) / 16+t (K); word base j0 in {8qa, 8qa+32}, 8 floats each.
    const int sw  = (t & 3) << 3;
    const int qrow = po + t * 64;
    const int krow = po + (16 + t) * 64;
    const int j0  = (8 * qa) ^ sw;              // swizzled base (bits 3..4)
    const int j1  = ((8 * qa + 32) ^ sw);

    short8 khi0, klo0, khi1, klo1, qhi0, qlo0, qhi1, qlo1;
    split8(*(const floatx4*)&lds[krow + j0], *(const floatx4*)&lds[krow + j0 + 4], khi0, klo0);
    split8(*(const floatx4*)&lds[krow + j1], *(const floatx4*)&lds[krow + j1 + 4], khi1, klo1);
    split8(*(const floatx4*)&lds[qrow + j0], *(const floatx4*)&lds[qrow + j0 + 4], qhi0, qlo0);
    split8(*(const floatx4*)&lds[qrow + j1], *(const floatx4*)&lds[qrow + j1 + 4], qhi1, qlo1);

    // ---- S^T = K * Q^T, 3-term split precision -----------------------------
    floatx4 sc = {0.f, 0.f, 0.f, 0.f};
    sc = __builtin_amdgcn_mfma_f32_16x16x32_bf16(khi0, qhi0, sc, 0, 0, 0);
    sc = __builtin_amdgcn_mfma_f32_16x16x32_bf16(khi1, qhi1, sc, 0, 0, 0);
    sc = __builtin_amdgcn_mfma_f32_16x16x32_bf16(khi0, qlo0, sc, 0, 0, 0);
    sc = __builtin_amdgcn_mfma_f32_16x16x32_bf16(khi1, qlo1, sc, 0, 0, 0);
    sc = __builtin_amdgcn_mfma_f32_16x16x32_bf16(klo0, qhi0, sc, 0, 0, 0);
    sc = __builtin_amdgcn_mfma_f32_16x16x32_bf16(klo1, qhi1, sc, 0, 0, 0);
    // sc[r] = raw_scores[h=t][g=4qa+r]

    // ---- softmax over g ----------------------------------------------------
    float s0 = sc[0] * 0.125f, s1 = sc[1] * 0.125f;
    float s2 = sc[2] * 0.125f, s3 = sc[3] * 0.125f;
    float m = fmaxf(fmaxf(s0, s1), fmaxf(s2, s3));
    m = fmaxf(m, __shfl_xor(m, 16));
    m = fmaxf(m, __shfl_xor(m, 32));
    float e0 = __expf(s0 - m), e1 = __expf(s1 - m);
    float e2 = __expf(s2 - m), e3 = __expf(s3 - m);
    float l = e0 + e1 + e2 + e3;
    l += __shfl_xor(l, 16);
    l += __shfl_xor(l, 32);
    float rl = 1.0f / l;
    float p0 = e0 * rl, p1 = e1 * rl, p2 = e2 * rl, p3 = e3 * rl;
    // lane holds attn[h=t][g=4*qa+r]

    // ---- redistribute attn into PV A-operand layout ------------------------
    int slo = (t + 32 * qa) & 63;
    int shi = (slo + 16) & 63;
    float av[8];
    av[0] = __shfl(p0, slo); av[1] = __shfl(p1, slo);
    av[2] = __shfl(p2, slo); av[3] = __shfl(p3, slo);
    av[4] = __shfl(p0, shi); av[5] = __shfl(p1, shi);
    av[6] = __shfl(p2, shi); av[7] = __shfl(p3, shi);
    const bool live = (qa < 2);
    short8 aph, apl;
    #pragma unroll
    for (int j = 0; j < 8; ++j) {
        short h = live ? f2bf(av[j]) : (short)0;
        aph[j] = h;
        apl[j] = live ? f2bf(av[j] - bf2f(h)) : (short)0;
    }

    // ---- PV from transposed V in LDS ---------------------------------------
    // bvh[j] <-> V[g = (8qa+j)&15][16c+t]; g0 = 8*(qa&1), 8 consecutive g.
    floatx4 o[4];
    #pragma unroll
    for (int c = 0; c < 4; ++c) {
        const int d = 16 * c + t;
        const int vb = po + 2048 + d * 16 + ((8 * (qa & 1)) ^ ((d & 1) << 3));
        floatx4 v0 = *(const floatx4*)&lds[vb];
        floatx4 v1 = *(const floatx4*)&lds[vb + 4];
        short8 bvh, bvl;
        split8(v0, v1, bvh, bvl);
        floatx4 z = {0.f, 0.f, 0.f, 0.f};
        z = __builtin_amdgcn_mfma_f32_16x16x32_bf16(aph, bvh, z, 0, 0, 0);
        z = __builtin_amdgcn_mfma_f32_16x16x32_bf16(aph, bvl, z, 0, 0, 0);
        z = __builtin_amdgcn_mfma_f32_16x16x32_bf16(apl, bvh, z, 0, 0, 0);
        o[c] = z;
    }
    // o[c][r] = out[h=4qa+r][d=16c+t]

    // ---- mask --------------------------------------------------------------
    const int f = *fmt;   // wave-uniform
    int mi;
    if (f == 0)       mi = (int)maskraw[wid];
    else if (f == 1)  mi = ((const int*)maskraw)[wid];
    else              mi = (int)(((const long long*)maskraw)[wid] != 0);
    const float mv = (mi != 0) ? 1.0f : 0.0f;

    // ---- stage output in LDS (reuse Q/K area), then coalesced store --------
    #pragma unroll
    for (int c = 0; c < 4; ++c) {
        #pragma unroll
        for (int r = 0; r < 4; ++r) {
            lds[po + (4 * qa + r) * 64 + c * 16 + t] = o[c][r] * mv;
        }
    }
    float* op = out + (size_t)wid * 1024;
    #pragma unroll
    for (int k = 0; k < 4; ++k) {
        floatx4 v = *(const floatx4*)&lds[po + k * 256 + lane * 4];
        *(floatx4*)(op + k * 256 + lane * 4) = v;
    }
}

extern "C" void kernel_launch(void* const* d_in, const int* in_sizes, int n_in,
                              void* d_out, int out_size, void* d_ws, size_t ws_size,
                              hipStream_t stream) {
    const float* qkv = (const float*)d_in[0];
    const unsigned char* maskraw = (const unsigned char*)d_in[1];
    float* out = (float*)d_out;
    int* fmt = (int*)d_ws;
    const int npos = in_sizes[1];               // B*S = 16384 positions

    detect_mask_fmt<<<1, 256, 0, stream>>>(maskraw, npos, fmt);

    const int blocks = (npos + 3) / 4;          // 4 positions per block
    fa_heads_kernel<<<blocks, 256, 0, stream>>>(qkv, maskraw, fmt, out, npos);
}